// Round 9
// baseline (301.355 us; speedup 1.0000x reference)
//
#include <hip/hip_runtime.h>
#include <hip/hip_bf16.h>
#include <math.h>
#include <stdint.h>

#define SEQL 4096
#define NH 16
#define CDIM 3072
#define DPROJ 3088
#define DMODEL 1024

typedef __bf16 nbf16;
typedef __attribute__((ext_vector_type(8))) __bf16 bf16x8;
typedef __attribute__((ext_vector_type(4))) float f32x4;

__device__ inline void store_val(float* p, float v) { *p = v; }
__device__ inline void store_val(nbf16* p, float v) { *p = (nbf16)v; }

__device__ __forceinline__ void gload_lds16(const void* g, void* l) {
  __builtin_amdgcn_global_load_lds(
      (const __attribute__((address_space(1))) void*)g,
      (__attribute__((address_space(3))) void*)l, 16, 0, 0);
}

// swizzled bf16 LDS index for [R][64] row-major tiles (16B-slot XOR)
__device__ __forceinline__ int swz(int row, int col) {
  return row * 64 + (col ^ ((row & 7) << 3));
}
// swizzled bf16 LDS index for [R][32] row-major tiles: rows r,r+2,..,r+6 spread
// across the 4 slots of each parity -> 2 lanes/bank (free) for 16-row col reads
__device__ __forceinline__ int swz32(int row, int col) {
  return row * 32 + (col ^ (((row >> 1) & 3) << 3));
}

// ---------------- bf16 MFMA GEMM: C[M,N] = A[M,K] @ B[N,K]^T ----------------
// 128x128 tile, 4 waves (2x2), 64x64/wave, BK=32, FOUR LDS buffers.
// T4 counted-vmcnt pipeline: stage tile t+3 while computing tile t; waits
// vmcnt(12) (3 tiles x 4 loads in flight) BEFORE compute; never drains to 0
// in the main loop. Raw s_barrier (no __syncthreads drain). T2 both-sides
// swizzle (linear LDS dest, pre-swizzled global source, swizzled reads).
template <typename TOUT>
__global__ __launch_bounds__(256) void gemm_mfma(const nbf16* __restrict__ A,
                                                 const nbf16* __restrict__ B,
                                                 TOUT* __restrict__ C,
                                                 int M, int N, int K) {
  __shared__ __align__(16) nbf16 Alds[4][128 * 32];
  __shared__ __align__(16) nbf16 Blds[4][128 * 32];
  int tid = threadIdx.x;
  int lane = tid & 63;
  int w = tid >> 6, wm = w >> 1, wn = w & 1;
  // T1 bijective XCD swizzle (nwg % 8 == 0)
  int gx = gridDim.x;
  int nwg = gx * gridDim.y;
  int orig = blockIdx.y * gx + blockIdx.x;
  int wg = (orig & 7) * (nwg >> 3) + (orig >> 3);
  int bm = (wg / gx) * 128, bn = (wg % gx) * 128;
  const nbf16* Ag = A + (size_t)bm * K;
  const nbf16* Bg = B + (size_t)bn * K;
  f32x4 acc[4][4] = {};
  const int nt = K >> 5;   // 32 for K=1024

  auto STAGE = [&](int buf, int t) {
#pragma unroll
    for (int q = 0; q < 2; ++q) {
      int e = (q * 256 + tid) * 8;           // element in 128x32 tile
      int row = e >> 5;
      int col = e & 31;
      int sc = col ^ (((row >> 1) & 3) << 3);  // pre-swizzled source col
      gload_lds16(Ag + (size_t)row * K + t * 32 + sc, &Alds[buf][e]);
      gload_lds16(Bg + (size_t)row * K + t * 32 + sc, &Blds[buf][e]);
    }
  };
  auto COMPUTE = [&](int buf) {
    bf16x8 af[4], bfr[4];
    int c0 = (lane >> 4) * 8;
#pragma unroll
    for (int i = 0; i < 4; ++i) {
      af[i]  = *(const bf16x8*)&Alds[buf][swz32(wm * 64 + i * 16 + (lane & 15), c0)];
      bfr[i] = *(const bf16x8*)&Blds[buf][swz32(wn * 64 + i * 16 + (lane & 15), c0)];
    }
    __builtin_amdgcn_s_setprio(1);
#pragma unroll
    for (int mi = 0; mi < 4; ++mi)
#pragma unroll
      for (int ni = 0; ni < 4; ++ni)
        acc[mi][ni] = __builtin_amdgcn_mfma_f32_16x16x32_bf16(af[mi], bfr[ni], acc[mi][ni], 0, 0, 0);
    __builtin_amdgcn_s_setprio(0);
  };

  STAGE(0, 0);
  STAGE(1, 1);
  STAGE(2, 2);
  for (int t = 0; t < nt; ++t) {
    if (t + 3 < nt) STAGE((t + 3) & 3, t + 3);
    int ahead = nt - 1 - t;
    if (ahead >= 3)      asm volatile("s_waitcnt vmcnt(12)" ::: "memory");
    else if (ahead == 2) asm volatile("s_waitcnt vmcnt(8)" ::: "memory");
    else if (ahead == 1) asm volatile("s_waitcnt vmcnt(4)" ::: "memory");
    else                 asm volatile("s_waitcnt vmcnt(0)" ::: "memory");
    __builtin_amdgcn_sched_barrier(0);
    __builtin_amdgcn_s_barrier();      // tile t fully staged for all waves
    COMPUTE(t & 3);
    __builtin_amdgcn_sched_barrier(0);
    __builtin_amdgcn_s_barrier();      // all waves done reading buf t&3
  }

#pragma unroll
  for (int mi = 0; mi < 4; ++mi)
#pragma unroll
    for (int ni = 0; ni < 4; ++ni) {
      int colw = bn + wn * 64 + ni * 16 + (lane & 15);
      if (colw >= N) continue;
#pragma unroll
      for (int j = 0; j < 4; ++j) {
        int roww = bm + wm * 64 + mi * 16 + (lane >> 4) * 4 + j;
        store_val(&C[(size_t)roww * N + colw], acc[mi][ni][j]);
      }
    }
}

// ---------------- f32 -> bf16 casts ----------------
__global__ __launch_bounds__(256) void cast_bf16(const float* __restrict__ in,
                                                 nbf16* __restrict__ out, long n) {
  long i = ((long)blockIdx.x * 256 + threadIdx.x) * 4;
  if (i >= n) return;
  float4 v = *(const float4*)(in + i);
  out[i] = (nbf16)v.x; out[i + 1] = (nbf16)v.y;
  out[i + 2] = (nbf16)v.z; out[i + 3] = (nbf16)v.w;
}

__global__ __launch_bounds__(256) void cast_pad_w(const float* __restrict__ in,
                                                  nbf16* __restrict__ out) {
  long i = ((long)blockIdx.x * 256 + threadIdx.x) * 4;
  if (i >= (long)3200 * 1024) return;
  int row = (int)(i >> 10);
  if (row < DPROJ) {
    float4 v = *(const float4*)(in + i);
    out[i] = (nbf16)v.x; out[i + 1] = (nbf16)v.y;
    out[i + 2] = (nbf16)v.z; out[i + 3] = (nbf16)v.w;
  } else {
    out[i] = (nbf16)0.f; out[i + 1] = (nbf16)0.f;
    out[i + 2] = (nbf16)0.f; out[i + 3] = (nbf16)0.f;
  }
}

// ---------------- intra-chunk SSD: conv + scalars + 3 MFMA matmuls ----------------
// grid: bid = b*1024 + c*16 + h (2048 blocks), 256 threads (4 waves)
__global__ __launch_bounds__(256) void ssd_intra(
    const nbf16* __restrict__ xw, const float* __restrict__ cw,
    const float* __restrict__ cb, const float* __restrict__ wbase,
    nbf16* __restrict__ Ydg, nbf16* __restrict__ stG,
    nbf16* __restrict__ Ccv,
    float* __restrict__ norm_diag, float* __restrict__ sdo_g,
    float* __restrict__ ndecay, float* __restrict__ Alast) {
  __shared__ __align__(16) nbf16 Craw[68 * 64];
  __shared__ __align__(16) nbf16 Braw[68 * 64];
  __shared__ __align__(16) nbf16 Xraw[68 * 64];
  __shared__ __align__(16) nbf16 BbT[64 * 64];
  __shared__ __align__(16) nbf16 XbT[64 * 64];
  __shared__ float cums_s[64], mincs_s[64], dec_s[64];
  nbf16* Sb = Xraw;

  int tid = threadIdx.x;
  int lane = tid & 63;
  int w = tid >> 6;
  int h = blockIdx.x & 15;
  int c = (blockIdx.x >> 4) & 63;
  int b = blockIdx.x >> 10;

  for (int i = tid; i < 67 * 8; i += 256) {
    int row = i >> 3, n0 = (i & 7) * 8;
    int t = c * 64 - 3 + row;
    bf16x8 vc = {}, vb = {}, vx = {};
    if (t >= 0) {
      const nbf16* r = xw + ((size_t)(b * SEQL + t)) * DPROJ + h * 64 + n0;
      vc = *(const bf16x8*)(r);
      vb = *(const bf16x8*)(r + 1024);
      vx = *(const bf16x8*)(r + 2048);
    }
    int idx = swz(row, n0);
    *(bf16x8*)&Craw[idx] = vc;
    *(bf16x8*)&Braw[idx] = vb;
    *(bf16x8*)&Xraw[idx] = vx;
  }

  if (w == 0) {
    float a = (float)xw[((size_t)(b * SEQL + c * 64 + lane)) * DPROJ + CDIM + h] * wbase[h];
    float cum = a;
#pragma unroll
    for (int d = 1; d < 64; d <<= 1) {
      float t = __shfl_up(cum, d, 64);
      if (lane >= d) cum += t;
    }
    float mn = cum;
#pragma unroll
    for (int d = 1; d < 64; d <<= 1) {
      float t = __shfl_up(mn, d, 64);
      if (lane >= d) mn = fminf(mn, t);
    }
    float mnall = __shfl(mn, 63, 64);
    float mx = cum;
#pragma unroll
    for (int d = 1; d < 64; d <<= 1) mx = fmaxf(mx, __shfl_xor(mx, d, 64));
    float dec = expf(mnall - cum);
    float sdo = expf(cum - mx);
    float nd = dec;
#pragma unroll
    for (int d = 1; d < 64; d <<= 1) nd += __shfl_xor(nd, d, 64);
    cums_s[lane] = cum; mincs_s[lane] = mn; dec_s[lane] = dec;
    sdo_g[(size_t)blockIdx.x * 64 + lane] = sdo;
    if (lane == 0) ndecay[blockIdx.x] = nd;
    if (lane == 63) Alast[((size_t)(b * NH + h)) * 64 + c] = cum;
  }
  __syncthreads();

  float rc[16], rb[16], rx[16];
  {
    int n = tid & 63, base = tid >> 6;
    const float* wcc = cw + (size_t)(h * 64 + n) * 4;
    const float* wcb = wcc + 4096;
    const float* wcx = wcc + 8192;
    float bcc = cb[h * 64 + n], bcb = cb[1024 + h * 64 + n], bcx = cb[2048 + h * 64 + n];
#pragma unroll
    for (int q = 0; q < 16; ++q) {
      int l = base + q * 4;
      float aC = bcc, aB = bcb, aX = bcx;
#pragma unroll
      for (int d = 0; d < 4; ++d) {
        int idx = swz(l + d, n);
        aC = fmaf((float)Craw[idx], wcc[d], aC);
        aB = fmaf((float)Braw[idx], wcb[d], aB);
        aX = fmaf((float)Xraw[idx], wcx[d], aX);
      }
      rc[q] = aC; rb[q] = aB; rx[q] = aX;
    }
  }
  __syncthreads();
  {
    int n = tid & 63, base = tid >> 6;
#pragma unroll
    for (int q = 0; q < 16; ++q) {
      int l = base + q * 4;
      nbf16 cv = (nbf16)rc[q];
      Craw[swz(l, n)] = cv;
      Braw[swz(l, n)] = (nbf16)rb[q];
      BbT[swz(n, l)] = (nbf16)rb[q];
      XbT[swz(n, l)] = (nbf16)rx[q];
      // cache conv'd C for ssd_off (coalesced 128B row-writes)
      Ccv[((size_t)(b * SEQL + c * 64 + l)) * DMODEL + h * 64 + n] = cv;
    }
  }
  __syncthreads();

  // matmul 1: S[l][s] = (C_l . B_s) * exp(mincs[l]-cums[s]), s<=l
  {
    f32x4 accS[4] = {};
#pragma unroll
    for (int kk = 0; kk < 64; kk += 32) {
      int arow = w * 16 + (lane & 15);
      int c0 = kk + (lane >> 4) * 8;
      bf16x8 af = *(const bf16x8*)&Craw[swz(arow, c0)];
#pragma unroll
      for (int nb = 0; nb < 4; ++nb) {
        int brow = nb * 16 + (lane & 15);
        bf16x8 bfr = *(const bf16x8*)&Braw[swz(brow, c0)];
        accS[nb] = __builtin_amdgcn_mfma_f32_16x16x32_bf16(af, bfr, accS[nb], 0, 0, 0);
      }
    }
    float rowsum[4] = {0.f, 0.f, 0.f, 0.f};
#pragma unroll
    for (int nb = 0; nb < 4; ++nb) {
      int s = nb * 16 + (lane & 15);
      float cs = cums_s[s];
#pragma unroll
      for (int r = 0; r < 4; ++r) {
        int l = w * 16 + (lane >> 4) * 4 + r;
        float e = (s <= l) ? expf(mincs_s[l] - cs) : 0.f;
        rowsum[r] += e;
        Sb[swz(l, s)] = (nbf16)(accS[nb][r] * e);
      }
    }
#pragma unroll
    for (int r = 0; r < 4; ++r) {
#pragma unroll
      for (int d = 1; d < 16; d <<= 1) rowsum[r] += __shfl_xor(rowsum[r], d, 64);
      if ((lane & 15) == 0) {
        int l = w * 16 + (lane >> 4) * 4 + r;
        norm_diag[(size_t)blockIdx.x * 64 + l] = rowsum[r];
      }
    }
  }
  __syncthreads();

  // matmul 2: Y_diag[l][p] = sum_s S[l][s] * X[s][p]  (bf16 out)
  {
    f32x4 accY[4] = {};
#pragma unroll
    for (int kk = 0; kk < 64; kk += 32) {
      int arow = w * 16 + (lane & 15);
      int c0 = kk + (lane >> 4) * 8;
      bf16x8 af = *(const bf16x8*)&Sb[swz(arow, c0)];
#pragma unroll
      for (int pb = 0; pb < 4; ++pb) {
        int prow = pb * 16 + (lane & 15);
        bf16x8 bfr = *(const bf16x8*)&XbT[swz(prow, c0)];
        accY[pb] = __builtin_amdgcn_mfma_f32_16x16x32_bf16(af, bfr, accY[pb], 0, 0, 0);
      }
    }
    size_t ybase = ((size_t)(b * SEQL + c * 64)) * DMODEL + h * 64;
#pragma unroll
    for (int pb = 0; pb < 4; ++pb) {
      int p = pb * 16 + (lane & 15);
#pragma unroll
      for (int r = 0; r < 4; ++r) {
        int l = w * 16 + (lane >> 4) * 4 + r;
        Ydg[ybase + (size_t)l * DMODEL + p] = (nbf16)accY[pb][r];
      }
    }
  }

  // matmul 3: states[p][n] = sum_l dec[l]*X[l][p]*B[l][n]  (bf16 out, [b,h,c,p*64+n])
  {
    f32x4 accT[4] = {};
#pragma unroll
    for (int kk = 0; kk < 64; kk += 32) {
      int prow = w * 16 + (lane & 15);
      int c0 = kk + (lane >> 4) * 8;
      bf16x8 xf = *(const bf16x8*)&XbT[swz(prow, c0)];
      bf16x8 af;
#pragma unroll
      for (int j = 0; j < 8; ++j) af[j] = (nbf16)((float)xf[j] * dec_s[c0 + j]);
#pragma unroll
      for (int nb = 0; nb < 4; ++nb) {
        int nrow = nb * 16 + (lane & 15);
        bf16x8 bfr = *(const bf16x8*)&BbT[swz(nrow, c0)];
        accT[nb] = __builtin_amdgcn_mfma_f32_16x16x32_bf16(af, bfr, accT[nb], 0, 0, 0);
      }
    }
    size_t sbase = (((size_t)(b * NH + h)) * 64 + c) * 4096;
#pragma unroll
    for (int nb = 0; nb < 4; ++nb) {
      int n = nb * 16 + (lane & 15);
#pragma unroll
      for (int r = 0; r < 4; ++r) {
        int p = w * 16 + (lane >> 4) * 4 + r;
        stG[sbase + p * 64 + n] = (nbf16)accT[nb][r];
      }
    }
  }
}

// ---------------- inter-chunk scan as MFMA matmul (IN PLACE on stG) ----------------
// grid: bid = ((b*16+h)*16 + et), 512 blocks, 256 threads (4 waves).
// Each block reads its whole et-slice into LDS before writing -> in-place safe.
__global__ __launch_bounds__(256) void ssd_scan(
    const float* __restrict__ Alast, nbf16* __restrict__ stG,
    const float* __restrict__ ndecay, float* __restrict__ nd_in) {
  __shared__ __align__(16) nbf16 Msw[64 * 64];
  __shared__ __align__(16) nbf16 StT[256 * 64];
  __shared__ float Qs[66], mzS[64];
  int tid = threadIdx.x, lane = tid & 63, w = tid >> 6;
  int et = blockIdx.x & 15, h = (blockIdx.x >> 4) & 15, b = blockIdx.x >> 8;

  if (w == 0) {
    float a = Alast[((size_t)(b * NH + h)) * 64 + lane];
    float s = a;
#pragma unroll
    for (int d = 1; d < 64; d <<= 1) {
      float t = __shfl_up(s, d, 64);
      if (lane >= d) s += t;
    }
    float Q = __shfl_up(s, 1, 64);
    if (lane == 0) Q = 0.f;
    float m = Q;
#pragma unroll
    for (int d = 1; d < 64; d <<= 1) {
      float t = __shfl_up(m, d, 64);
      if (lane >= d) m = fminf(m, t);
    }
    Qs[lane] = Q; mzS[lane] = m;
    if (lane == 0) { Qs[64] = 0.f; Qs[65] = 0.f; }
  }
  __syncthreads();

#pragma unroll
  for (int k = 0; k < 16; ++k) {
    int i = tid + (k << 8);
    int z = i >> 6, j = i & 63;
    float v = (j < z) ? expf(mzS[z] - Qs[j + 1]) : 0.f;
    Msw[swz(z, j)] = (nbf16)v;
  }
  size_t stbase = ((size_t)(b * NH + h)) * 64 * 4096 + et * 256;
#pragma unroll
  for (int q = 0; q < 8; ++q) {
    int i = tid + (q << 8);
    int cc = i >> 5, oct = i & 31;
    bf16x8 v = *(const bf16x8*)&stG[stbase + (size_t)cc * 4096 + oct * 8];
#pragma unroll
    for (int jj = 0; jj < 8; ++jj) StT[swz(oct * 8 + jj, cc)] = v[jj];
  }
  __syncthreads();

  if (et == 0 && tid < 64) {
    int z = tid;
    float acc = 0.f;
    for (int j = 0; j < z; ++j)
      acc += expf(mzS[z] - Qs[j + 1]) * ndecay[((size_t)(b * 64 + j)) * 16 + h];
    nd_in[((size_t)(b * 64 + z)) * 16 + h] = acc;
  }

  f32x4 acc[4][4] = {};
#pragma unroll
  for (int kk = 0; kk < 64; kk += 32) {
    int c0 = kk + (lane >> 4) * 8;
    bf16x8 af[4], bfr[4];
#pragma unroll
    for (int i = 0; i < 4; ++i) {
      af[i]  = *(const bf16x8*)&Msw[swz(i * 16 + (lane & 15), c0)];
      bfr[i] = *(const bf16x8*)&StT[swz(w * 64 + i * 16 + (lane & 15), c0)];
    }
#pragma unroll
    for (int mi = 0; mi < 4; ++mi)
#pragma unroll
      for (int ni = 0; ni < 4; ++ni)
        acc[mi][ni] = __builtin_amdgcn_mfma_f32_16x16x32_bf16(af[mi], bfr[ni], acc[mi][ni], 0, 0, 0);
  }
  size_t obase = stbase;
#pragma unroll
  for (int mi = 0; mi < 4; ++mi)
#pragma unroll
    for (int ni = 0; ni < 4; ++ni) {
      int e = w * 64 + ni * 16 + (lane & 15);
#pragma unroll
      for (int r = 0; r < 4; ++r) {
        int z = mi * 16 + (lane >> 4) * 4 + r;
        stG[obase + (size_t)z * 4096 + e] = (nbf16)acc[mi][ni][r];
      }
    }
}

// ---------------- off-diagonal + combine (MFMA), conv'd C cached ----------------
__global__ __launch_bounds__(256) void ssd_off(
    const nbf16* __restrict__ Ccv, const nbf16* __restrict__ siG,
    const float* __restrict__ norm_diag, const float* __restrict__ sdo_g,
    const float* __restrict__ nd_in, nbf16* __restrict__ Ydg) {
  __shared__ __align__(16) nbf16 Csw[64 * 64];
  __shared__ __align__(16) nbf16 Ssb[64 * 64];
  int tid = threadIdx.x, lane = tid & 63, w = tid >> 6;
  int h = blockIdx.x & 15, c = (blockIdx.x >> 4) & 63, b = blockIdx.x >> 10;

  for (int i = tid; i < 512; i += 256) {
    int row = i >> 3, n0 = (i & 7) * 8;
    bf16x8 v = *(const bf16x8*)&Ccv[((size_t)(b * SEQL + c * 64 + row)) * DMODEL + h * 64 + n0];
    *(bf16x8*)&Csw[swz(row, n0)] = v;
  }
  {
    size_t sbase = (((size_t)(b * NH + h)) * 64 + c) * 4096;
    for (int i = tid; i < 512; i += 256) {
      int p = i >> 3, n0 = (i & 7) * 8;
      bf16x8 v = *(const bf16x8*)&siG[sbase + p * 64 + n0];
      *(bf16x8*)&Ssb[swz(p, n0)] = v;
    }
  }
  __syncthreads();

  f32x4 accO[4] = {};
#pragma unroll
  for (int kk = 0; kk < 64; kk += 32) {
    int arow = w * 16 + (lane & 15);
    int c0 = kk + (lane >> 4) * 8;
    bf16x8 af = *(const bf16x8*)&Csw[swz(arow, c0)];
#pragma unroll
    for (int pb = 0; pb < 4; ++pb) {
      int prow = pb * 16 + (lane & 15);
      bf16x8 bfr = *(const bf16x8*)&Ssb[swz(prow, c0)];
      accO[pb] = __builtin_amdgcn_mfma_f32_16x16x32_bf16(af, bfr, accO[pb], 0, 0, 0);
    }
  }
  float ndin = nd_in[blockIdx.x];
  size_t ybase = ((size_t)(b * SEQL + c * 64)) * DMODEL + h * 64;
#pragma unroll
  for (int r = 0; r < 4; ++r) {
    int l = w * 16 + (lane >> 4) * 4 + r;
    float sd = sdo_g[(size_t)blockIdx.x * 64 + l];
    float nrm = norm_diag[(size_t)blockIdx.x * 64 + l] + ndin * sd;
#pragma unroll
    for (int pb = 0; pb < 4; ++pb) {
      int p = pb * 16 + (lane & 15);
      size_t yi = ybase + (size_t)l * DMODEL + p;
      Ydg[yi] = (nbf16)(((float)Ydg[yi] + accO[pb][r] * sd) / nrm);
    }
  }
}

extern "C" void kernel_launch(void* const* d_in, const int* in_sizes, int n_in,
                              void* d_out, int out_size, void* d_ws, size_t ws_size,
                              hipStream_t stream) {
  const float* x          = (const float*)d_in[0];
  const float* in_proj_w  = (const float*)d_in[1];
  const float* conv_w     = (const float*)d_in[2];
  const float* conv_b     = (const float*)d_in[3];
  const float* w_base     = (const float*)d_in[4];
  const float* out_proj_w = (const float*)d_in[5];
  float* out = (float*)d_out;

  char* ws = (char*)d_ws;
  size_t off = 0;
  auto alloc = [&](size_t bytes) {
    void* p = ws + off;
    off += (bytes + 255) & ~(size_t)255;
    return p;
  };
  const size_t BT = (size_t)2 * SEQL;                        // 8192
  nbf16* xIOw = (nbf16*)alloc(BT * DPROJ * 2);               // 50.6 MB
  nbf16* xbf  = (nbf16*)alloc(BT * DMODEL * 2);              // 16.8 MB (reused as Ydg/Y)
  nbf16* wibf = (nbf16*)alloc((size_t)3200 * 1024 * 2);      // 6.6 MB
  nbf16* wobf = (nbf16*)alloc((size_t)1024 * 1024 * 2);      // 2.1 MB
  nbf16* stG  = (nbf16*)alloc((size_t)2048 * 4096 * 2);      // 16.8 MB (scan in place)
  nbf16* Ccv  = (nbf16*)alloc(BT * DMODEL * 2);              // 16.8 MB
  float* norm_diag = (float*)alloc((size_t)2048 * 64 * 4);
  float* sdo   = (float*)alloc((size_t)2048 * 64 * 4);
  float* ndec  = (float*)alloc((size_t)2048 * 4);
  float* Alast = (float*)alloc((size_t)2048 * 4);
  float* nd_in = (float*)alloc((size_t)2048 * 4);
  nbf16* Ydg = xbf;   // xbf dead after in-proj GEMM; Ydg updated in place by ssd_off
  // total ~110.8 MB (same proven budget as R4-R7)

  cast_bf16<<<(int)(BT * DMODEL / 4 / 256), 256, 0, stream>>>(x, xbf, BT * DMODEL);
  cast_pad_w<<<3200 * 1024 / 4 / 256, 256, 0, stream>>>(in_proj_w, wibf);
  cast_bf16<<<DMODEL * DMODEL / 4 / 256, 256, 0, stream>>>(out_proj_w, wobf, (long)DMODEL * DMODEL);
  // in-proj: grid 25 x 64 (1600 blocks, %8==0)
  gemm_mfma<nbf16><<<dim3(25, BT / 128), 256, 0, stream>>>(
      xbf, wibf, xIOw, (int)BT, DPROJ, DMODEL);
  ssd_intra<<<2048, 256, 0, stream>>>(xIOw, conv_w, conv_b, w_base,
                                      Ydg, stG, Ccv, norm_diag, sdo, ndec, Alast);
  ssd_scan<<<512, 256, 0, stream>>>(Alast, stG, ndec, nd_in);
  ssd_off<<<2048, 256, 0, stream>>>(Ccv, stG, norm_diag, sdo, nd_in, Ydg);
  // out-proj: grid 8 x 64 (512 blocks)
  gemm_mfma<float><<<dim3(DMODEL / 128, BT / 128), 256, 0, stream>>>(
      Ydg, wobf, out, (int)BT, DMODEL, DMODEL);
}